// Round 11
// baseline (224.264 us; speedup 1.0000x reference)
//
#include <hip/hip_runtime.h>

typedef unsigned short u16;
typedef __attribute__((ext_vector_type(8))) short short8;
typedef __attribute__((ext_vector_type(4))) float f32x4;
typedef __attribute__((ext_vector_type(4))) u16 ushort4t;
typedef __attribute__((ext_vector_type(8))) u16 ushort8t;
typedef __attribute__((ext_vector_type(2))) unsigned uint2t;

#define MFMA16(a,b,c) __builtin_amdgcn_mfma_f32_16x16x32_bf16((a),(b),(c),0,0,0)

#define GLD16(gp, lp) __builtin_amdgcn_global_load_lds( \
    (__attribute__((address_space(1))) void*)(gp), \
    (__attribute__((address_space(3))) void*)(lp), 16, 0, 0)

__device__ __forceinline__ u16 f2bf(float f){
  unsigned u = __float_as_uint(f);
  u += 0x7FFFu + ((u>>16)&1u);
  return (u16)(u>>16);
}
__device__ __forceinline__ float bf2f(u16 h){
  return __uint_as_float(((unsigned)h)<<16);
}
__device__ __forceinline__ unsigned cvtpk(float a, float b){
  unsigned r; asm("v_cvt_pk_bf16_f32 %0, %1, %2" : "=v"(r) : "v"(a), "v"(b));
  return r;
}

// ---- geometry ----
#define NB 4
#define NH 8
#define CD 64
#define LS 2048
#define NBH 32
#define NPOS 8192
#define NOCH 1536

// ---- workspace offsets (bytes) ----
#define O_WB    0x000000
#define O_BEFF  0x040000
#define O_UWB   0x050000
#define O_WCB   0x080000
#define O_BDYN  0x090000
#define O_XT    0x100000
#define O_QT    0x200000
#define O_KT    0xA00000
#define O_VB    0x1200000
#define O_AB    0x2A00000
#define O_DB    0x3200000

// =====================================================================
// Prep: fold depthwise into pointwise, gate-softmax, bf16 conversions.
// Q weights additionally scaled by log2(e) -> QK^T emits log2-domain
// scores; attn uses exp2 directly (saves a v_mul per exp).
// =====================================================================
__global__ __launch_bounds__(256) void prep_kernel(
    const float* qdw, const float* qdb, const float* qpw, const float* qpb,
    const float* kdw, const float* kdb, const float* kpw, const float* kpb,
    const float* vdw, const float* vdb, const float* vpw, const float* vpb,
    const float* c0pw, const float* c0db, const float* c0pb,
    const float* c1pw, const float* c1db, const float* c1pb,
    const float* gate, const float* uw,
    u16* Wb, float* beff, u16* uwb, u16* Wcb, float* bdyn)
{
  const float QSCL = 0.125f * 1.44269504088896f;   // scale^2 * log2(e)
  int tid = blockIdx.x*256 + threadIdx.x;
  float gm = fmaxf(gate[0], gate[1]);
  float e0 = __expf(gate[0]-gm), e1 = __expf(gate[1]-gm);
  float g0 = e0/(e0+e1), g1 = e1/(e0+e1);
  if (tid < 98304){
    int o = tid>>6, c = tid&63;
    int p = o>>9, orr = o&511;
    const float* pw = (p==0)? qpw : (p==1)? kpw : vpw;
    const float* dw = (p==0)? qdw : (p==1)? kdw : vdw;
    float v = pw[orr*64+c]*dw[c];
    if (p==0) v *= QSCL;
    Wb[tid] = f2bf(v);
  } else if (tid < 99840){
    int o = tid - 98304;
    int p = o>>9, orr = o&511;
    const float* pw = (p==0)? qpw : (p==1)? kpw : vpw;
    const float* db = (p==0)? qdb : (p==1)? kdb : vdb;
    const float* pb = (p==0)? qpb : (p==1)? kpb : vpb;
    float s = pb[orr];
    for (int c=0;c<64;++c) s += pw[orr*64+c]*db[c];
    if (p==0) s *= QSCL;
    beff[o] = s;
  } else if (tid < 165376){
    int i = tid - 99840;
    uwb[i] = f2bf(uw[i]);
  } else if (tid < 173568){
    int i = tid - 165376;          // 0..8191: [o][c2], c2 = k*64+c
    int o = i>>7, c2 = i&127, k = c2>>6, c = c2&63;
    float wv = k ? (g1*c1pw[o*64+c]) : (g0*c0pw[o*64+c]);
    Wcb[i] = f2bf(wv);
  } else if (tid < 173632){
    int o = tid - 173568;
    float s = g0*c0pb[o] + g1*c1pb[o];
    for (int c=0;c<64;++c) s += g0*c0pw[o*64+c]*c0db[c] + g1*c1pw[o*64+c]*c1db[c];
    bdyn[o] = s;
  }
}

// =====================================================================
// Transpose x (B,C,L) f32 -> xt (B,L,C) bf16
// =====================================================================
__global__ __launch_bounds__(256) void transpose_kernel(const float* x, u16* xt){
  __shared__ float tile[64][65];
  int t = threadIdx.x;
  int l0 = blockIdx.x*64, b = blockIdx.y;
  #pragma unroll
  for (int j=0;j<4;++j){
    int fl = t + j*256;
    int c = fl>>4, qd = fl&15;
    f32x4 v = *(const f32x4*)(x + ((size_t)(b*64+c))*LS + l0 + qd*4);
    tile[c][qd*4+0]=v[0]; tile[c][qd*4+1]=v[1]; tile[c][qd*4+2]=v[2]; tile[c][qd*4+3]=v[3];
  }
  __syncthreads();
  int l = t>>2, cg = t&3;
  ushort8t a, bv;
  #pragma unroll
  for (int j=0;j<8;++j) a[j] = f2bf(tile[cg*16+j][l]);
  #pragma unroll
  for (int j=0;j<8;++j) bv[j] = f2bf(tile[cg*16+8+j][l]);
  u16* dst = xt + ((size_t)(b*LS + l0 + l))*64 + cg*16;
  *(ushort8t*)dst = a;
  *(ushort8t*)(dst+8) = bv;
}

// =====================================================================
// QKV projection GEMM: (1536x64)@(64x8192)
// =====================================================================
__global__ __launch_bounds__(256) void proj_kernel(const u16* Wb, const float* beff, const u16* xt,
    u16* Qt, u16* Kt, u16* Vb)
{
  int tid = threadIdx.x, w = tid>>6, lane = tid&63;
  int q16 = lane&15, g = lane>>4;
  int o0 = blockIdx.y*128 + (w>>1)*64;
  int p0 = blockIdx.x*128 + (w&1)*64;
  short8 af[4][2], bfr[4][2];
  #pragma unroll
  for (int mt=0;mt<4;++mt)
    #pragma unroll
    for (int s=0;s<2;++s)
      af[mt][s] = *(const short8*)(Wb + (size_t)(o0+mt*16+q16)*64 + s*32 + g*8);
  #pragma unroll
  for (int nt=0;nt<4;++nt)
    #pragma unroll
    for (int s=0;s<2;++s)
      bfr[nt][s] = *(const short8*)(xt + (size_t)(p0+nt*16+q16)*64 + s*32 + g*8);
  f32x4 acc[4][4];
  #pragma unroll
  for (int mt=0;mt<4;++mt)
    #pragma unroll
    for (int nt=0;nt<4;++nt) acc[mt][nt] = (f32x4){0.f,0.f,0.f,0.f};
  #pragma unroll
  for (int s=0;s<2;++s)
    #pragma unroll
    for (int mt=0;mt<4;++mt)
      #pragma unroll
      for (int nt=0;nt<4;++nt)
        acc[mt][nt] = MFMA16(af[mt][s], bfr[nt][s], acc[mt][nt]);
  #pragma unroll
  for (int mt=0;mt<4;++mt){
    int obase = o0 + mt*16;
    int p = obase>>9;
    int h = (obase>>6)&7;
    int c0 = (obase&63) + g*4;
    f32x4 bvv = *(const f32x4*)(beff + obase + g*4);
    #pragma unroll
    for (int nt=0;nt<4;++nt){
      int pos = p0 + nt*16 + q16;
      int b = pos>>11, l = pos&2047;
      int bh = b*8 + h;
      float v0 = acc[mt][nt][0]+bvv[0], v1 = acc[mt][nt][1]+bvv[1],
            v2 = acc[mt][nt][2]+bvv[2], v3 = acc[mt][nt][3]+bvv[3];
      if (p==0){
        ushort4t pk = {f2bf(v0),f2bf(v1),f2bf(v2),f2bf(v3)};
        *(ushort4t*)(Qt + ((size_t)(bh*LS+l))*64 + c0) = pk;
      } else if (p==1){
        ushort4t pk = {f2bf(v0),f2bf(v1),f2bf(v2),f2bf(v3)};
        *(ushort4t*)(Kt + ((size_t)(bh*LS+l))*64 + c0) = pk;
      } else {
        size_t base = ((size_t)(bh*64+c0))*LS + l;
        Vb[base]      = f2bf(v0);
        Vb[base+LS]   = f2bf(v1);
        Vb[base+2*LS] = f2bf(v2);
        Vb[base+3*LS] = f2bf(v3);
      }
    }
  }
}

// =====================================================================
// Flash attention, softmax over keys. 4 waves x 32 queries = 128 q/block.
// K/V staged once per 128 q (GLD16/wave halved), counted vmcnt(4).
// Lazy cross-lane max (shfls only when max grows) + deferred l-sum
// (epilogue-only reduce) shorten the per-tile serial chain. exp2 domain.
// XCD-aware block swizzle: 4 bh per XCD -> K/V L2-resident per XCD.
// =====================================================================
__global__ __launch_bounds__(256) void attn_kernel(const u16* Qt, const u16* Kt, const u16* Vb, u16* Ab)
{
  __shared__ __align__(16) char lds[49152]; // K 2x8K, V 2x8K, P 4 waves x 4K
  const int tid = threadIdx.x;
  const int w = tid>>6, lane = tid&63;
  const int q16 = lane&15, g = lane>>4;
  const int bid = blockIdx.x;
  const int sw = (bid&7)*64 + (bid>>3);   // bijective: 512 = 8*64
  const int qtile = sw & 15, bh = sw >> 4;
  const int q0 = qtile*128 + w*32;
  char* ldsK = lds;
  char* ldsV = lds + 16384;
  char* ldsP = lds + 32768 + w*4096;

  short8 qf[2][2];
  #pragma unroll
  for (int qg=0;qg<2;++qg){
    const u16* qb = Qt + ((size_t)(bh*LS + q0 + qg*16 + q16))*64 + g*8;
    qf[qg][0] = *(const short8*)qb;
    qf[qg][1] = *(const short8*)(qb + 32);
  }

  float mrun[2] = {-1e30f,-1e30f}, lrun[2] = {0.f,0.f};
  f32x4 oacc[2][4];
  #pragma unroll
  for (int qg=0;qg<2;++qg)
    #pragma unroll
    for (int i=0;i<4;++i) oacc[qg][i] = (f32x4){0.f,0.f,0.f,0.f};

  // staging: wave w covers K rows {w*8..w*8+7, 32+w*8..} and same V rows;
  // per instr dest = base + lane*16 (linear, rule #21); source pre-swizzled.
  const int srow = w*8 + (lane>>3);      // 0..31, srow&7 == lane>>3
  const int chunk = lane&7;
  const int sch = chunk ^ (lane>>3);     // involution XOR on 16B chunks
  const int swzq = q16&7;

  // prologue: stage tile 0 into buffer 0
  GLD16(Kt + ((size_t)(bh*LS + srow))*64      + sch*8, ldsK + w*1024 + lane*16);
  GLD16(Kt + ((size_t)(bh*LS + 32 + srow))*64 + sch*8, ldsK + 4096 + w*1024 + lane*16);
  GLD16(Vb + ((size_t)(bh*64 + srow))*LS      + sch*8, ldsV + w*1024 + lane*16);
  GLD16(Vb + ((size_t)(bh*64 + 32 + srow))*LS + sch*8, ldsV + 4096 + w*1024 + lane*16);

  int cur = 0;
  for (int kt=0; kt<32; ++kt){
    if (kt+1 < 32){
      int k0 = (kt+1)*64;
      int nb = (cur^1)*8192;
      GLD16(Kt + ((size_t)(bh*LS + k0 + srow))*64      + sch*8, ldsK + nb + w*1024 + lane*16);
      GLD16(Kt + ((size_t)(bh*LS + k0 + 32 + srow))*64 + sch*8, ldsK + nb + 4096 + w*1024 + lane*16);
      GLD16(Vb + ((size_t)(bh*64 + srow))*LS + k0      + sch*8, ldsV + nb + w*1024 + lane*16);
      GLD16(Vb + ((size_t)(bh*64 + 32 + srow))*LS + k0 + sch*8, ldsV + nb + 4096 + w*1024 + lane*16);
      asm volatile("s_waitcnt vmcnt(4)" ::: "memory");  // tile kt landed; kt+1 in flight
    } else {
      asm volatile("s_waitcnt vmcnt(0)" ::: "memory");
    }
    __builtin_amdgcn_s_barrier();   // B1: kt data visible block-wide
    char* lK = ldsK + cur*8192;
    char* lV = ldsV + cur*8192;

    // QK^T: S[key, q] via mfma(K, Q); K-frags shared by both q-groups
    f32x4 s[2][4];
    #pragma unroll
    for (int qg=0;qg<2;++qg)
      #pragma unroll
      for (int i=0;i<4;++i) s[qg][i] = (f32x4){0.f,0.f,0.f,0.f};
    __builtin_amdgcn_s_setprio(1);
    #pragma unroll
    for (int ss=0; ss<2; ++ss){
      #pragma unroll
      for (int mt=0; mt<4; ++mt){
        short8 kf = *(short8*)(lK + (mt*16+q16)*128 + (((ss*4+g)^swzq)<<4));
        s[0][mt] = MFMA16(kf, qf[0][ss], s[0][mt]);
        s[1][mt] = MFMA16(kf, qf[1][ss], s[1][mt]);
      }
    }
    __builtin_amdgcn_s_setprio(0);

    // online softmax (log2 domain); lazy cross-lane max, deferred sum
    #pragma unroll
    for (int qg=0;qg<2;++qg){
      float tmax = fmaxf(fmaxf(s[qg][0][0],s[qg][0][1]), fmaxf(s[qg][0][2],s[qg][0][3]));
      #pragma unroll
      for (int mt=1;mt<4;++mt)
        tmax = fmaxf(tmax, fmaxf(fmaxf(s[qg][mt][0],s[qg][mt][1]), fmaxf(s[qg][mt][2],s[qg][mt][3])));
      if (__any(tmax > mrun[qg])){
        tmax = fmaxf(tmax, __shfl_xor(tmax,16));
        tmax = fmaxf(tmax, __shfl_xor(tmax,32));
        float mnew = fmaxf(mrun[qg], tmax);
        float corr = exp2f(mrun[qg] - mnew);
        lrun[qg] *= corr;
        #pragma unroll
        for (int i=0;i<4;++i) oacc[qg][i] *= corr;
        mrun[qg] = mnew;
      }
      float ps = 0.f;
      #pragma unroll
      for (int mt=0;mt<4;++mt){
        #pragma unroll
        for (int r=0;r<4;++r){
          float p = exp2f(s[qg][mt][r]-mrun[qg]);
          s[qg][mt][r] = p; ps += p;
        }
      }
      lrun[qg] += ps;   // per-lane partial; reduced at epilogue

      // P -> LDS strip [q][key] (bf16, swizzled) via packed cvt
      #pragma unroll
      for (int mt=0;mt<4;++mt){
        uint2t pk = { cvtpk(s[qg][mt][0], s[qg][mt][1]),
                      cvtpk(s[qg][mt][2], s[qg][mt][3]) };
        int cw = (2*mt + (g>>1)) ^ swzq;
        *(uint2t*)(ldsP + qg*2048 + q16*128 + (cw<<4) + (g&1)*8) = pk;
      }
    }

    // PV: V-frags shared by both q-groups
    __builtin_amdgcn_s_setprio(1);
    #pragma unroll
    for (int half=0; half<2; ++half){
      short8 pf0 = *(short8*)(ldsP +        q16*128 + (((half*4+g)^swzq)<<4));
      short8 pf1 = *(short8*)(ldsP + 2048 + q16*128 + (((half*4+g)^swzq)<<4));
      #pragma unroll
      for (int ct=0;ct<4;++ct){
        short8 vf = *(short8*)(lV + (ct*16+q16)*128 + (((half*4+g)^swzq)<<4));
        oacc[0][ct] = MFMA16(vf, pf0, oacc[0][ct]);
        oacc[1][ct] = MFMA16(vf, pf1, oacc[1][ct]);
      }
    }
    __builtin_amdgcn_s_setprio(0);
    __builtin_amdgcn_s_barrier();   // B2: reads of buf[cur] complete
    cur ^= 1;
  }
  #pragma unroll
  for (int qg=0;qg<2;++qg){
    float lr = lrun[qg];
    lr += __shfl_xor(lr,16);
    lr += __shfl_xor(lr,32);
    float inv = 1.f/lr;
    u16* ab = Ab + ((size_t)(bh*LS + q0 + qg*16 + q16))*64;
    #pragma unroll
    for (int ct=0;ct<4;++ct){
      ushort4t ov = {f2bf(oacc[qg][ct][0]*inv),f2bf(oacc[qg][ct][1]*inv),
                     f2bf(oacc[qg][ct][2]*inv),f2bf(oacc[qg][ct][3]*inv)};
      *(ushort4t*)(ab + ct*16 + g*4) = ov;
    }
  }
}

// =====================================================================
// Dynamic conv branch, MFMA pointwise (unchanged from round 6)
// =====================================================================
__global__ __launch_bounds__(256) void dyn_kernel(const u16* Vb, const float* d0w, const float* d1w,
    const u16* Wcb, const float* bdyn, u16* Db)
{
  __shared__ __align__(16) u16 Y[16384]; // [l][c2] 128x128
  const int t = threadIdx.x;
  const int bh = blockIdx.y;
  const int l0 = blockIdx.x*128;
  const int c = t>>2, sub = t&3;
  const int base = l0 + sub*32 - 8;      // 16B-aligned
  const u16* vrow = Vb + (size_t)(bh*64 + c)*LS;

  u16 vwin[48];
  if (base >= 0 && base + 48 <= 2048){
    #pragma unroll
    for (int k=0;k<6;++k)
      *(ushort8t*)(vwin + k*8) = *(const ushort8t*)(vrow + base + k*8);
  } else {
    #pragma unroll
    for (int k=0;k<48;++k){
      int gi = base + k;
      vwin[k] = ((unsigned)gi < 2048u) ? vrow[gi] : (u16)0;
    }
  }
  float fw[48];
  #pragma unroll
  for (int k=0;k<48;++k) fw[k] = bf2f(vwin[k]);
  float w1[15], w0[3];
  #pragma unroll
  for (int k=0;k<15;++k) w1[k] = d1w[c*15+k];
  #pragma unroll
  for (int k=0;k<3;++k)  w0[k] = d0w[c*3+k];

  const int chi = c>>3, clo = c&7;
  #pragma unroll
  for (int j=0;j<32;++j){
    float a1 = 0.f;
    #pragma unroll
    for (int k=0;k<15;++k) a1 += fw[j+1+k]*w1[k];
    float a0 = fw[j+7]*w0[0] + fw[j+8]*w0[1] + fw[j+9]*w0[2];
    int lloc = sub*32 + j;
    int swl = lloc&7;
    Y[lloc*128 + (chi^swl)*8 + clo]     = f2bf(a0);   // c2 = c
    Y[lloc*128 + ((8+chi)^swl)*8 + clo] = f2bf(a1);   // c2 = 64+c
  }
  __syncthreads();

  const int w = t>>6, lane = t&63;
  const int q16 = lane&15, g = lane>>4;
  short8 af[4][4];
  #pragma unroll
  for (int mt=0;mt<4;++mt)
    #pragma unroll
    for (int ks=0;ks<4;++ks)
      af[mt][ks] = *(const short8*)(Wcb + (mt*16+q16)*128 + ks*32 + g*8);
  f32x4 acc[4][2];
  #pragma unroll
  for (int mt=0;mt<4;++mt){ acc[mt][0]=(f32x4){0.f,0.f,0.f,0.f}; acc[mt][1]=(f32x4){0.f,0.f,0.f,0.f}; }
  #pragma unroll
  for (int ks=0;ks<4;++ks){
    #pragma unroll
    for (int nt=0;nt<2;++nt){
      int pos = w*32 + nt*16 + q16;
      int ch = (ks*4+g) ^ (pos&7);
      short8 bf = *(const short8*)(&Y[pos*128 + ch*8]);
      #pragma unroll
      for (int mt=0;mt<4;++mt)
        acc[mt][nt] = MFMA16(af[mt][ks], bf, acc[mt][nt]);
    }
  }
  #pragma unroll
  for (int mt=0;mt<4;++mt){
    f32x4 bv = *(const f32x4*)(bdyn + mt*16 + g*4);
    #pragma unroll
    for (int nt=0;nt<2;++nt){
      int pos = l0 + w*32 + nt*16 + q16;
      ushort4t pk = {f2bf(acc[mt][nt][0]+bv[0]), f2bf(acc[mt][nt][1]+bv[1]),
                     f2bf(acc[mt][nt][2]+bv[2]), f2bf(acc[mt][nt][3]+bv[3])};
      *(ushort4t*)(Db + ((size_t)(bh*LS+pos))*64 + mt*16 + g*4) = pk;
    }
  }
}

// =====================================================================
// Unify heads: (64 x 1024) @ (1024 x 8192) bf16 MFMA GEMM + bias.
// 512 blocks x 16 pos; 4 waves = 4-way split-K (8 ks each); LDS reduce.
// =====================================================================
__global__ __launch_bounds__(256) void unify_kernel(const u16* uwb, const float* ub,
    const u16* Ab, const u16* Db, float* out)
{
  __shared__ f32x4 red[3][4][64];
  int tid = threadIdx.x, kh = tid>>6, lane = tid&63;
  int q16 = lane&15, g = lane>>4;
  int pos = blockIdx.x*16 + q16;
  int b = pos>>11, pl = pos&2047;
  f32x4 acc[4];
  #pragma unroll
  for (int i=0;i<4;++i) acc[i]=(f32x4){0.f,0.f,0.f,0.f};
  #pragma unroll
  for (int i=0;i<8;++i){
    int ks = kh*8 + i;
    int ch = ks*32 + g*8;
    const u16* src;
    if (ks < 16){
      src = Ab + ((size_t)((b*8 + (ch>>6))*LS + pl))*64 + (ch&63);
    } else {
      int c2 = ch - 512;
      src = Db + ((size_t)((b*8 + (c2>>6))*LS + pl))*64 + (c2&63);
    }
    short8 bf = *(const short8*)src;
    #pragma unroll
    for (int mt=0;mt<4;++mt){
      short8 af = *(const short8*)(uwb + (size_t)(mt*16+q16)*1024 + ks*32 + g*8);
      acc[mt] = MFMA16(af, bf, acc[mt]);
    }
  }
  if (kh > 0){
    #pragma unroll
    for (int mt=0;mt<4;++mt) red[kh-1][mt][lane] = acc[mt];
  }
  __syncthreads();
  if (kh == 0){
    #pragma unroll
    for (int mt=0;mt<4;++mt){
      f32x4 a = acc[mt];
      a += red[0][mt][lane];
      a += red[1][mt][lane];
      a += red[2][mt][lane];
      #pragma unroll
      for (int r=0;r<4;++r){
        int o = mt*16 + g*4 + r;
        out[((size_t)(b*64+o))*LS + pl] = a[r] + ub[o];
      }
    }
  }
}

extern "C" void kernel_launch(void* const* d_in, const int* in_sizes, int n_in,
                              void* d_out, int out_size, void* d_ws, size_t ws_size,
                              hipStream_t stream)
{
  const float* x    = (const float*)d_in[0];
  const float* qdw  = (const float*)d_in[1];
  const float* qdb  = (const float*)d_in[2];
  const float* qpw  = (const float*)d_in[3];
  const float* qpb  = (const float*)d_in[4];
  const float* kdw  = (const float*)d_in[5];
  const float* kdb  = (const float*)d_in[6];
  const float* kpw  = (const float*)d_in[7];
  const float* kpb  = (const float*)d_in[8];
  const float* vdw  = (const float*)d_in[9];
  const float* vdb  = (const float*)d_in[10];
  const float* vpw  = (const float*)d_in[11];
  const float* vpb  = (const float*)d_in[12];
  const float* c0dw = (const float*)d_in[13];
  const float* c0db = (const float*)d_in[14];
  const float* c0pw = (const float*)d_in[15];
  const float* c0pb = (const float*)d_in[16];
  const float* c1dw = (const float*)d_in[17];
  const float* c1db = (const float*)d_in[18];
  const float* c1pw = (const float*)d_in[19];
  const float* c1pb = (const float*)d_in[20];
  const float* gate = (const float*)d_in[21];
  const float* uw   = (const float*)d_in[22];
  const float* ubias= (const float*)d_in[23];
  float* out = (float*)d_out;
  char* ws = (char*)d_ws;

  u16*   Wb   = (u16*)(ws + O_WB);
  float* beff = (float*)(ws + O_BEFF);
  u16*   uwb  = (u16*)(ws + O_UWB);
  u16*   Wcb  = (u16*)(ws + O_WCB);
  float* bdyn = (float*)(ws + O_BDYN);
  u16*   xt   = (u16*)(ws + O_XT);
  u16*   Qt   = (u16*)(ws + O_QT);
  u16*   Kt   = (u16*)(ws + O_KT);
  u16*   Vb   = (u16*)(ws + O_VB);
  u16*   Ab   = (u16*)(ws + O_AB);
  u16*   Db   = (u16*)(ws + O_DB);

  prep_kernel<<<dim3(679), dim3(256), 0, stream>>>(
      qdw,qdb,qpw,qpb, kdw,kdb,kpw,kpb, vdw,vdb,vpw,vpb,
      c0pw,c0db,c0pb, c1pw,c1db,c1pb, gate, uw,
      Wb, beff, uwb, Wcb, bdyn);
  transpose_kernel<<<dim3(32,4), dim3(256), 0, stream>>>(x, xt);
  proj_kernel<<<dim3(64,12), dim3(256), 0, stream>>>(Wb, beff, xt, Qt, Kt, Vb);
  attn_kernel<<<dim3(512), dim3(256), 0, stream>>>(Qt, Kt, Vb, Ab);
  dyn_kernel<<<dim3(16,32), dim3(256), 0, stream>>>(Vb, c0dw, c1dw, Wcb, bdyn, Db);
  unify_kernel<<<dim3(512), dim3(256), 0, stream>>>(uwb, ubias, Ab, Db, out);
}

// Round 13
// 207.398 us; speedup vs baseline: 1.0813x; 1.0813x over previous
//
#include <hip/hip_runtime.h>

typedef unsigned short u16;
typedef __attribute__((ext_vector_type(8))) short short8;
typedef __attribute__((ext_vector_type(4))) float f32x4;
typedef __attribute__((ext_vector_type(4))) u16 ushort4t;
typedef __attribute__((ext_vector_type(8))) u16 ushort8t;
typedef __attribute__((ext_vector_type(2))) unsigned uint2t;

#define MFMA16(a,b,c) __builtin_amdgcn_mfma_f32_16x16x32_bf16((a),(b),(c),0,0,0)

#define GLD16(gp, lp) __builtin_amdgcn_global_load_lds( \
    (__attribute__((address_space(1))) void*)(gp), \
    (__attribute__((address_space(3))) void*)(lp), 16, 0, 0)

__device__ __forceinline__ u16 f2bf(float f){
  unsigned u = __float_as_uint(f);
  u += 0x7FFFu + ((u>>16)&1u);
  return (u16)(u>>16);
}
__device__ __forceinline__ float bf2f(u16 h){
  return __uint_as_float(((unsigned)h)<<16);
}
__device__ __forceinline__ unsigned cvtpk(float a, float b){
  unsigned r; asm("v_cvt_pk_bf16_f32 %0, %1, %2" : "=v"(r) : "v"(a), "v"(b));
  return r;
}

// Native 2^x: exactly one v_exp_f32 (quarter-rate VALU), no OCML libcall.
extern "C" __device__ float __ocml_native_exp2_f32(float);
__device__ __forceinline__ float fexp2(float x){
#if __has_builtin(__builtin_amdgcn_exp2f)
  return __builtin_amdgcn_exp2f(x);
#else
  return __ocml_native_exp2_f32(x);
#endif
}
// 3-input max; clang fuses nested fmaxf into v_max3_f32.
__device__ __forceinline__ float fmax3(float a, float b, float c){
  return fmaxf(fmaxf(a,b),c);
}

// ---- geometry ----
#define NB 4
#define NH 8
#define CD 64
#define LS 2048
#define NBH 32
#define NPOS 8192
#define NOCH 1536

// ---- workspace offsets (bytes) ----
#define O_WB    0x000000
#define O_BEFF  0x040000
#define O_UWB   0x050000
#define O_WCB   0x080000
#define O_BDYN  0x090000
#define O_XT    0x100000
#define O_QT    0x200000
#define O_KT    0xA00000
#define O_VB    0x1200000
#define O_AB    0x2A00000
#define O_DB    0x3200000

// =====================================================================
// Prep: fold depthwise into pointwise, gate-softmax, bf16 conversions.
// Q weights scaled by scale^2*log2(e) -> QK^T emits log2-domain scores.
// =====================================================================
__global__ __launch_bounds__(256) void prep_kernel(
    const float* qdw, const float* qdb, const float* qpw, const float* qpb,
    const float* kdw, const float* kdb, const float* kpw, const float* kpb,
    const float* vdw, const float* vdb, const float* vpw, const float* vpb,
    const float* c0pw, const float* c0db, const float* c0pb,
    const float* c1pw, const float* c1db, const float* c1pb,
    const float* gate, const float* uw,
    u16* Wb, float* beff, u16* uwb, u16* Wcb, float* bdyn)
{
  const float QSCL = 0.125f * 1.44269504088896f;   // scale^2 * log2(e)
  int tid = blockIdx.x*256 + threadIdx.x;
  float gm = fmaxf(gate[0], gate[1]);
  float e0 = __expf(gate[0]-gm), e1 = __expf(gate[1]-gm);
  float g0 = e0/(e0+e1), g1 = e1/(e0+e1);
  if (tid < 98304){
    int o = tid>>6, c = tid&63;
    int p = o>>9, orr = o&511;
    const float* pw = (p==0)? qpw : (p==1)? kpw : vpw;
    const float* dw = (p==0)? qdw : (p==1)? kdw : vdw;
    float v = pw[orr*64+c]*dw[c];
    if (p==0) v *= QSCL;
    Wb[tid] = f2bf(v);
  } else if (tid < 99840){
    int o = tid - 98304;
    int p = o>>9, orr = o&511;
    const float* pw = (p==0)? qpw : (p==1)? kpw : vpw;
    const float* db = (p==0)? qdb : (p==1)? kdb : vdb;
    const float* pb = (p==0)? qpb : (p==1)? kpb : vpb;
    float s = pb[orr];
    for (int c=0;c<64;++c) s += pw[orr*64+c]*db[c];
    if (p==0) s *= QSCL;
    beff[o] = s;
  } else if (tid < 165376){
    int i = tid - 99840;
    uwb[i] = f2bf(uw[i]);
  } else if (tid < 173568){
    int i = tid - 165376;          // 0..8191: [o][c2], c2 = k*64+c
    int o = i>>7, c2 = i&127, k = c2>>6, c = c2&63;
    float wv = k ? (g1*c1pw[o*64+c]) : (g0*c0pw[o*64+c]);
    Wcb[i] = f2bf(wv);
  } else if (tid < 173632){
    int o = tid - 173568;
    float s = g0*c0pb[o] + g1*c1pb[o];
    for (int c=0;c<64;++c) s += g0*c0pw[o*64+c]*c0db[c] + g1*c1pw[o*64+c]*c1db[c];
    bdyn[o] = s;
  }
}

// =====================================================================
// Transpose x (B,C,L) f32 -> xt (B,L,C) bf16
// =====================================================================
__global__ __launch_bounds__(256) void transpose_kernel(const float* x, u16* xt){
  __shared__ float tile[64][65];
  int t = threadIdx.x;
  int l0 = blockIdx.x*64, b = blockIdx.y;
  #pragma unroll
  for (int j=0;j<4;++j){
    int fl = t + j*256;
    int c = fl>>4, qd = fl&15;
    f32x4 v = *(const f32x4*)(x + ((size_t)(b*64+c))*LS + l0 + qd*4);
    tile[c][qd*4+0]=v[0]; tile[c][qd*4+1]=v[1]; tile[c][qd*4+2]=v[2]; tile[c][qd*4+3]=v[3];
  }
  __syncthreads();
  int l = t>>2, cg = t&3;
  ushort8t a, bv;
  #pragma unroll
  for (int j=0;j<8;++j) a[j] = f2bf(tile[cg*16+j][l]);
  #pragma unroll
  for (int j=0;j<8;++j) bv[j] = f2bf(tile[cg*16+8+j][l]);
  u16* dst = xt + ((size_t)(b*LS + l0 + l))*64 + cg*16;
  *(ushort8t*)dst = a;
  *(ushort8t*)(dst+8) = bv;
}

// =====================================================================
// QKV projection GEMM: (1536x64)@(64x8192)
// =====================================================================
__global__ __launch_bounds__(256) void proj_kernel(const u16* Wb, const float* beff, const u16* xt,
    u16* Qt, u16* Kt, u16* Vb)
{
  int tid = threadIdx.x, w = tid>>6, lane = tid&63;
  int q16 = lane&15, g = lane>>4;
  int o0 = blockIdx.y*128 + (w>>1)*64;
  int p0 = blockIdx.x*128 + (w&1)*64;
  short8 af[4][2], bfr[4][2];
  #pragma unroll
  for (int mt=0;mt<4;++mt)
    #pragma unroll
    for (int s=0;s<2;++s)
      af[mt][s] = *(const short8*)(Wb + (size_t)(o0+mt*16+q16)*64 + s*32 + g*8);
  #pragma unroll
  for (int nt=0;nt<4;++nt)
    #pragma unroll
    for (int s=0;s<2;++s)
      bfr[nt][s] = *(const short8*)(xt + (size_t)(p0+nt*16+q16)*64 + s*32 + g*8);
  f32x4 acc[4][4];
  #pragma unroll
  for (int mt=0;mt<4;++mt)
    #pragma unroll
    for (int nt=0;nt<4;++nt) acc[mt][nt] = (f32x4){0.f,0.f,0.f,0.f};
  #pragma unroll
  for (int s=0;s<2;++s)
    #pragma unroll
    for (int mt=0;mt<4;++mt)
      #pragma unroll
      for (int nt=0;nt<4;++nt)
        acc[mt][nt] = MFMA16(af[mt][s], bfr[nt][s], acc[mt][nt]);
  #pragma unroll
  for (int mt=0;mt<4;++mt){
    int obase = o0 + mt*16;
    int p = obase>>9;
    int h = (obase>>6)&7;
    int c0 = (obase&63) + g*4;
    f32x4 bvv = *(const f32x4*)(beff + obase + g*4);
    #pragma unroll
    for (int nt=0;nt<4;++nt){
      int pos = p0 + nt*16 + q16;
      int b = pos>>11, l = pos&2047;
      int bh = b*8 + h;
      float v0 = acc[mt][nt][0]+bvv[0], v1 = acc[mt][nt][1]+bvv[1],
            v2 = acc[mt][nt][2]+bvv[2], v3 = acc[mt][nt][3]+bvv[3];
      if (p==0){
        ushort4t pk = {f2bf(v0),f2bf(v1),f2bf(v2),f2bf(v3)};
        *(ushort4t*)(Qt + ((size_t)(bh*LS+l))*64 + c0) = pk;
      } else if (p==1){
        ushort4t pk = {f2bf(v0),f2bf(v1),f2bf(v2),f2bf(v3)};
        *(ushort4t*)(Kt + ((size_t)(bh*LS+l))*64 + c0) = pk;
      } else {
        size_t base = ((size_t)(bh*64+c0))*LS + l;
        Vb[base]      = f2bf(v0);
        Vb[base+LS]   = f2bf(v1);
        Vb[base+2*LS] = f2bf(v2);
        Vb[base+3*LS] = f2bf(v3);
      }
    }
  }
}

// =====================================================================
// Flash attention, softmax over keys. 4 waves x 32 queries = 128 q/block.
// Counted vmcnt(4) double-buffer; lazy cross-lane max; deferred l-sum;
// XCD-aware swizzle. VALU-thinned softmax: native v_exp_f32 (no OCML
// libcall), v_max3 tree, 4-way partial sums.
// =====================================================================
__global__ __launch_bounds__(256) void attn_kernel(const u16* Qt, const u16* Kt, const u16* Vb, u16* Ab)
{
  __shared__ __align__(16) char lds[49152]; // K 2x8K, V 2x8K, P 4 waves x 4K
  const int tid = threadIdx.x;
  const int w = tid>>6, lane = tid&63;
  const int q16 = lane&15, g = lane>>4;
  const int bid = blockIdx.x;
  const int sw = (bid&7)*64 + (bid>>3);   // bijective: 512 = 8*64
  const int qtile = sw & 15, bh = sw >> 4;
  const int q0 = qtile*128 + w*32;
  char* ldsK = lds;
  char* ldsV = lds + 16384;
  char* ldsP = lds + 32768 + w*4096;

  short8 qf[2][2];
  #pragma unroll
  for (int qg=0;qg<2;++qg){
    const u16* qb = Qt + ((size_t)(bh*LS + q0 + qg*16 + q16))*64 + g*8;
    qf[qg][0] = *(const short8*)qb;
    qf[qg][1] = *(const short8*)(qb + 32);
  }

  float mrun[2] = {-1e30f,-1e30f}, lrun[2] = {0.f,0.f};
  f32x4 oacc[2][4];
  #pragma unroll
  for (int qg=0;qg<2;++qg)
    #pragma unroll
    for (int i=0;i<4;++i) oacc[qg][i] = (f32x4){0.f,0.f,0.f,0.f};

  // staging: dest = base + lane*16 (linear, rule #21); source pre-swizzled.
  const int srow = w*8 + (lane>>3);      // 0..31, srow&7 == lane>>3
  const int chunk = lane&7;
  const int sch = chunk ^ (lane>>3);     // involution XOR on 16B chunks
  const int swzq = q16&7;

  // prologue: stage tile 0 into buffer 0
  GLD16(Kt + ((size_t)(bh*LS + srow))*64      + sch*8, ldsK + w*1024 + lane*16);
  GLD16(Kt + ((size_t)(bh*LS + 32 + srow))*64 + sch*8, ldsK + 4096 + w*1024 + lane*16);
  GLD16(Vb + ((size_t)(bh*64 + srow))*LS      + sch*8, ldsV + w*1024 + lane*16);
  GLD16(Vb + ((size_t)(bh*64 + 32 + srow))*LS + sch*8, ldsV + 4096 + w*1024 + lane*16);

  int cur = 0;
  for (int kt=0; kt<32; ++kt){
    if (kt+1 < 32){
      int k0 = (kt+1)*64;
      int nb = (cur^1)*8192;
      GLD16(Kt + ((size_t)(bh*LS + k0 + srow))*64      + sch*8, ldsK + nb + w*1024 + lane*16);
      GLD16(Kt + ((size_t)(bh*LS + k0 + 32 + srow))*64 + sch*8, ldsK + nb + 4096 + w*1024 + lane*16);
      GLD16(Vb + ((size_t)(bh*64 + srow))*LS + k0      + sch*8, ldsV + nb + w*1024 + lane*16);
      GLD16(Vb + ((size_t)(bh*64 + 32 + srow))*LS + k0 + sch*8, ldsV + nb + 4096 + w*1024 + lane*16);
      asm volatile("s_waitcnt vmcnt(4)" ::: "memory");  // tile kt landed; kt+1 in flight
    } else {
      asm volatile("s_waitcnt vmcnt(0)" ::: "memory");
    }
    __builtin_amdgcn_s_barrier();   // B1: kt data visible block-wide
    char* lK = ldsK + cur*8192;
    char* lV = ldsV + cur*8192;

    // QK^T: S[key, q] via mfma(K, Q); K-frags shared by both q-groups
    f32x4 s[2][4];
    #pragma unroll
    for (int qg=0;qg<2;++qg)
      #pragma unroll
      for (int i=0;i<4;++i) s[qg][i] = (f32x4){0.f,0.f,0.f,0.f};
    __builtin_amdgcn_s_setprio(1);
    #pragma unroll
    for (int ss=0; ss<2; ++ss){
      #pragma unroll
      for (int mt=0; mt<4; ++mt){
        short8 kf = *(short8*)(lK + (mt*16+q16)*128 + (((ss*4+g)^swzq)<<4));
        s[0][mt] = MFMA16(kf, qf[0][ss], s[0][mt]);
        s[1][mt] = MFMA16(kf, qf[1][ss], s[1][mt]);
      }
    }
    __builtin_amdgcn_s_setprio(0);

    // online softmax (log2 domain); lazy cross-lane max, deferred sum
    #pragma unroll
    for (int qg=0;qg<2;++qg){
      // v_max3 tree over 16 values: 8 insts
      float t0 = fmax3(s[qg][0][0], s[qg][0][1], s[qg][0][2]);
      float t1 = fmax3(s[qg][0][3], s[qg][1][0], s[qg][1][1]);
      float t2 = fmax3(s[qg][1][2], s[qg][1][3], s[qg][2][0]);
      float t3 = fmax3(s[qg][2][1], s[qg][2][2], s[qg][2][3]);
      float t4 = fmax3(s[qg][3][0], s[qg][3][1], s[qg][3][2]);
      float tmax = fmaxf(fmax3(fmax3(t0,t1,t2), t3, t4), s[qg][3][3]);
      if (__any(tmax > mrun[qg])){
        tmax = fmaxf(tmax, __shfl_xor(tmax,16));
        tmax = fmaxf(tmax, __shfl_xor(tmax,32));
        float mnew = fmaxf(mrun[qg], tmax);
        float corr = fexp2(mrun[qg] - mnew);
        lrun[qg] *= corr;
        #pragma unroll
        for (int i=0;i<4;++i) oacc[qg][i] *= corr;
        mrun[qg] = mnew;
      }
      // exp via single v_exp_f32 each; 4-way partial sums for ILP
      float ps0 = 0.f, ps1 = 0.f, ps2 = 0.f, ps3 = 0.f;
      #pragma unroll
      for (int mt=0;mt<4;++mt){
        float p0 = fexp2(s[qg][mt][0]-mrun[qg]);
        float p1 = fexp2(s[qg][mt][1]-mrun[qg]);
        float p2 = fexp2(s[qg][mt][2]-mrun[qg]);
        float p3 = fexp2(s[qg][mt][3]-mrun[qg]);
        s[qg][mt][0]=p0; s[qg][mt][1]=p1; s[qg][mt][2]=p2; s[qg][mt][3]=p3;
        ps0 += p0; ps1 += p1; ps2 += p2; ps3 += p3;
      }
      lrun[qg] += (ps0+ps1) + (ps2+ps3);   // per-lane partial; epilogue reduce

      // P -> LDS strip [q][key] (bf16, swizzled) via packed cvt
      #pragma unroll
      for (int mt=0;mt<4;++mt){
        uint2t pk = { cvtpk(s[qg][mt][0], s[qg][mt][1]),
                      cvtpk(s[qg][mt][2], s[qg][mt][3]) };
        int cw = (2*mt + (g>>1)) ^ swzq;
        *(uint2t*)(ldsP + qg*2048 + q16*128 + (cw<<4) + (g&1)*8) = pk;
      }
    }

    // PV: V-frags shared by both q-groups
    __builtin_amdgcn_s_setprio(1);
    #pragma unroll
    for (int half=0; half<2; ++half){
      short8 pf0 = *(short8*)(ldsP +        q16*128 + (((half*4+g)^swzq)<<4));
      short8 pf1 = *(short8*)(ldsP + 2048 + q16*128 + (((half*4+g)^swzq)<<4));
      #pragma unroll
      for (int ct=0;ct<4;++ct){
        short8 vf = *(short8*)(lV + (ct*16+q16)*128 + (((half*4+g)^swzq)<<4));
        oacc[0][ct] = MFMA16(vf, pf0, oacc[0][ct]);
        oacc[1][ct] = MFMA16(vf, pf1, oacc[1][ct]);
      }
    }
    __builtin_amdgcn_s_setprio(0);
    __builtin_amdgcn_s_barrier();   // B2: reads of buf[cur] complete
    cur ^= 1;
  }
  #pragma unroll
  for (int qg=0;qg<2;++qg){
    float lr = lrun[qg];
    lr += __shfl_xor(lr,16);
    lr += __shfl_xor(lr,32);
    float inv = 1.f/lr;
    u16* ab = Ab + ((size_t)(bh*LS + q0 + qg*16 + q16))*64;
    #pragma unroll
    for (int ct=0;ct<4;++ct){
      ushort4t ov = {f2bf(oacc[qg][ct][0]*inv),f2bf(oacc[qg][ct][1]*inv),
                     f2bf(oacc[qg][ct][2]*inv),f2bf(oacc[qg][ct][3]*inv)};
      *(ushort4t*)(ab + ct*16 + g*4) = ov;
    }
  }
}

// =====================================================================
// Dynamic conv branch, MFMA pointwise (unchanged)
// =====================================================================
__global__ __launch_bounds__(256) void dyn_kernel(const u16* Vb, const float* d0w, const float* d1w,
    const u16* Wcb, const float* bdyn, u16* Db)
{
  __shared__ __align__(16) u16 Y[16384]; // [l][c2] 128x128
  const int t = threadIdx.x;
  const int bh = blockIdx.y;
  const int l0 = blockIdx.x*128;
  const int c = t>>2, sub = t&3;
  const int base = l0 + sub*32 - 8;      // 16B-aligned
  const u16* vrow = Vb + (size_t)(bh*64 + c)*LS;

  u16 vwin[48];
  if (base >= 0 && base + 48 <= 2048){
    #pragma unroll
    for (int k=0;k<6;++k)
      *(ushort8t*)(vwin + k*8) = *(const ushort8t*)(vrow + base + k*8);
  } else {
    #pragma unroll
    for (int k=0;k<48;++k){
      int gi = base + k;
      vwin[k] = ((unsigned)gi < 2048u) ? vrow[gi] : (u16)0;
    }
  }
  float fw[48];
  #pragma unroll
  for (int k=0;k<48;++k) fw[k] = bf2f(vwin[k]);
  float w1[15], w0[3];
  #pragma unroll
  for (int k=0;k<15;++k) w1[k] = d1w[c*15+k];
  #pragma unroll
  for (int k=0;k<3;++k)  w0[k] = d0w[c*3+k];

  const int chi = c>>3, clo = c&7;
  #pragma unroll
  for (int j=0;j<32;++j){
    float a1 = 0.f;
    #pragma unroll
    for (int k=0;k<15;++k) a1 += fw[j+1+k]*w1[k];
    float a0 = fw[j+7]*w0[0] + fw[j+8]*w0[1] + fw[j+9]*w0[2];
    int lloc = sub*32 + j;
    int swl = lloc&7;
    Y[lloc*128 + (chi^swl)*8 + clo]     = f2bf(a0);   // c2 = c
    Y[lloc*128 + ((8+chi)^swl)*8 + clo] = f2bf(a1);   // c2 = 64+c
  }
  __syncthreads();

  const int w = t>>6, lane = t&63;
  const int q16 = lane&15, g = lane>>4;
  short8 af[4][4];
  #pragma unroll
  for (int mt=0;mt<4;++mt)
    #pragma unroll
    for (int ks=0;ks<4;++ks)
      af[mt][ks] = *(const short8*)(Wcb + (mt*16+q16)*128 + ks*32 + g*8);
  f32x4 acc[4][2];
  #pragma unroll
  for (int mt=0;mt<4;++mt){ acc[mt][0]=(f32x4){0.f,0.f,0.f,0.f}; acc[mt][1]=(f32x4){0.f,0.f,0.f,0.f}; }
  #pragma unroll
  for (int ks=0;ks<4;++ks){
    #pragma unroll
    for (int nt=0;nt<2;++nt){
      int pos = w*32 + nt*16 + q16;
      int ch = (ks*4+g) ^ (pos&7);
      short8 bf = *(const short8*)(&Y[pos*128 + ch*8]);
      #pragma unroll
      for (int mt=0;mt<4;++mt)
        acc[mt][nt] = MFMA16(af[mt][ks], bf, acc[mt][nt]);
    }
  }
  #pragma unroll
  for (int mt=0;mt<4;++mt){
    f32x4 bv = *(const f32x4*)(bdyn + mt*16 + g*4);
    #pragma unroll
    for (int nt=0;nt<2;++nt){
      int pos = l0 + w*32 + nt*16 + q16;
      ushort4t pk = {f2bf(acc[mt][nt][0]+bv[0]), f2bf(acc[mt][nt][1]+bv[1]),
                     f2bf(acc[mt][nt][2]+bv[2]), f2bf(acc[mt][nt][3]+bv[3])};
      *(ushort4t*)(Db + ((size_t)(bh*LS+pos))*64 + mt*16 + g*4) = pk;
    }
  }
}

// =====================================================================
// Unify heads: (64 x 1024) @ (1024 x 8192) bf16 MFMA GEMM + bias.
// 512 blocks x 16 pos; 4 waves = 4-way split-K (8 ks each); LDS reduce.
// =====================================================================
__global__ __launch_bounds__(256) void unify_kernel(const u16* uwb, const float* ub,
    const u16* Ab, const u16* Db, float* out)
{
  __shared__ f32x4 red[3][4][64];
  int tid = threadIdx.x, kh = tid>>6, lane = tid&63;
  int q16 = lane&15, g = lane>>4;
  int pos = blockIdx.x*16 + q16;
  int b = pos>>11, pl = pos&2047;
  f32x4 acc[4];
  #pragma unroll
  for (int i=0;i<4;++i) acc[i]=(f32x4){0.f,0.f,0.f,0.f};
  #pragma unroll
  for (int i=0;i<8;++i){
    int ks = kh*8 + i;
    int ch = ks*32 + g*8;
    const u16* src;
    if (ks < 16){
      src = Ab + ((size_t)((b*8 + (ch>>6))*LS + pl))*64 + (ch&63);
    } else {
      int c2 = ch - 512;
      src = Db + ((size_t)((b*8 + (c2>>6))*LS + pl))*64 + (c2&63);
    }
    short8 bf = *(const short8*)src;
    #pragma unroll
    for (int mt=0;mt<4;++mt){
      short8 af = *(const short8*)(uwb + (size_t)(mt*16+q16)*1024 + ks*32 + g*8);
      acc[mt] = MFMA16(af, bf, acc[mt]);
    }
  }
  if (kh > 0){
    #pragma unroll
    for (int mt=0;mt<4;++mt) red[kh-1][mt][lane] = acc[mt];
  }
  __syncthreads();
  if (kh == 0){
    #pragma unroll
    for (int mt=0;mt<4;++mt){
      f32x4 a = acc[mt];
      a += red[0][mt][lane];
      a += red[1][mt][lane];
      a += red[2][mt][lane];
      #pragma unroll
      for (int r=0;r<4;++r){
        int o = mt*16 + g*4 + r;
        out[((size_t)(b*64+o))*LS + pl] = a[r] + ub[o];
      }
    }
  }
}

extern "C" void kernel_launch(void* const* d_in, const int* in_sizes, int n_in,
                              void* d_out, int out_size, void* d_ws, size_t ws_size,
                              hipStream_t stream)
{
  const float* x    = (const float*)d_in[0];
  const float* qdw  = (const float*)d_in[1];
  const float* qdb  = (const float*)d_in[2];
  const float* qpw  = (const float*)d_in[3];
  const float* qpb  = (const float*)d_in[4];
  const float* kdw  = (const float*)d_in[5];
  const float* kdb  = (const float*)d_in[6];
  const float* kpw  = (const float*)d_in[7];
  const float* kpb  = (const float*)d_in[8];
  const float* vdw  = (const float*)d_in[9];
  const float* vdb  = (const float*)d_in[10];
  const float* vpw  = (const float*)d_in[11];
  const float* vpb  = (const float*)d_in[12];
  const float* c0dw = (const float*)d_in[13];
  const float* c0db = (const float*)d_in[14];
  const float* c0pw = (const float*)d_in[15];
  const float* c0pb = (const float*)d_in[16];
  const float* c1dw = (const float*)d_in[17];
  const float* c1db = (const float*)d_in[18];
  const float* c1pw = (const float*)d_in[19];
  const float* c1pb = (const float*)d_in[20];
  const float* gate = (const float*)d_in[21];
  const float* uw   = (const float*)d_in[22];
  const float* ubias= (const float*)d_in[23];
  float* out = (float*)d_out;
  char* ws = (char*)d_ws;

  u16*   Wb   = (u16*)(ws + O_WB);
  float* beff = (float*)(ws + O_BEFF);
  u16*   uwb  = (u16*)(ws + O_UWB);
  u16*   Wcb  = (u16*)(ws + O_WCB);
  float* bdyn = (float*)(ws + O_BDYN);
  u16*   xt   = (u16*)(ws + O_XT);
  u16*   Qt   = (u16*)(ws + O_QT);
  u16*   Kt   = (u16*)(ws + O_KT);
  u16*   Vb   = (u16*)(ws + O_VB);
  u16*   Ab   = (u16*)(ws + O_AB);
  u16*   Db   = (u16*)(ws + O_DB);

  prep_kernel<<<dim3(679), dim3(256), 0, stream>>>(
      qdw,qdb,qpw,qpb, kdw,kdb,kpw,kpb, vdw,vdb,vpw,vpb,
      c0pw,c0db,c0pb, c1pw,c1db,c1pb, gate, uw,
      Wb, beff, uwb, Wcb, bdyn);
  transpose_kernel<<<dim3(32,4), dim3(256), 0, stream>>>(x, xt);
  proj_kernel<<<dim3(64,12), dim3(256), 0, stream>>>(Wb, beff, xt, Qt, Kt, Vb);
  attn_kernel<<<dim3(512), dim3(256), 0, stream>>>(Qt, Kt, Vb, Ab);
  dyn_kernel<<<dim3(16,32), dim3(256), 0, stream>>>(Vb, c0dw, c1dw, Wcb, bdyn, Db);
  unify_kernel<<<dim3(512), dim3(256), 0, stream>>>(uwb, ubias, Ab, Db, out);
}